// Round 2
// baseline (1736.337 us; speedup 1.0000x reference)
//
#include <hip/hip_runtime.h>

// Shifted-window MSA, fixed shape: B=16, H=W=56, C=256, NH=8, hd=32, WS=7, SS=3.
// 56%7==0 -> no padding. 1024 windows of 49 tokens.
// Inputs are FP32 (per reference dtypes): query(16,3136,256), w_qkv(256,768),
// b_qkv(768), w_proj(256,256), b_proj(256), rel_bias_table(169,8), height, width.
// Output FP32 (16,3136,256). d_ws holds pre-projection attention output O as
// bf16: 1024*49*256*2 = 25.7 MB.

#define NHEADS 8
#define HD 32
#define CDIM 256
#define NTOK 49
#define IMG 56
#define NWIN 1024
#define SCALE 0.17677669529663687f

typedef unsigned short u16;
typedef unsigned int u32;

__device__ __forceinline__ float bflo(u32 u) { return __uint_as_float(u << 16); }
__device__ __forceinline__ float bfhi(u32 u) { return __uint_as_float(u & 0xffff0000u); }
__device__ __forceinline__ u16 f2bf(float f) {
  u32 u = __float_as_uint(f);
  return (u16)((u + 0x7fffu + ((u >> 16) & 1u)) >> 16);  // RNE
}

// ---------------- Kernel 1: fused shifted-window QKV + attention ----------------
// LDS: Xs 25872 + Qs 7056 + Kt 6784 + Vs 7056 + Ss 9800 + biasf 5408 + cls 196
//    = 62172 B  (< 64 KB static limit; 1 block/CU)
__global__ __launch_bounds__(256) void attn_kernel(
    const float* __restrict__ query, const float* __restrict__ w_qkv,
    const float* __restrict__ b_qkv, const float* __restrict__ bias_table,
    u16* __restrict__ O) {
  __shared__ __align__(16) u16 Xs[NTOK][264];  // window tokens as bf16, +8 pad
  __shared__ float Qs[NTOK][36];               // q (pre-scaled), row-major
  __shared__ float Kt[HD][53];                 // k transposed [d][m]
  __shared__ float Vs[NTOK][36];               // v row-major
  __shared__ float Ss[NTOK][50];               // scores / probs
  __shared__ float biasf[169 * 8];             // rel-pos bias table (fp32)
  __shared__ int cls[NTOK];                    // shift-mask region class

  const int tid = threadIdx.x;
  const int win = blockIdx.x;
  const int b  = win >> 6;
  const int wi = (win >> 3) & 7;
  const int wj = win & 7;

  // stage rel-pos bias table (fp32 copy)
  for (int t = tid; t < 169 * 8; t += 256) biasf[t] = bias_table[t];

  // shift-mask region classes (rolled-image coordinates)
  if (tid < NTOK) {
    int pr = tid / 7, pc = tid % 7;
    int rc = (wi < 7) ? 0 : ((pr < 4) ? 1 : 2);
    int cc = (wj < 7) ? 0 : ((pc < 4) ? 1 : 2);
    cls[tid] = rc * 3 + cc;
  }

  // stage X (fp32 global -> bf16 LDS): rolled[hs][ws] = x[(hs+3)%56][(ws+3)%56]
  for (int t = tid; t < NTOK * 64; t += 256) {  // 49 rows x 64 float4-groups
    int r = t >> 6, ch = t & 63;
    int pr = r / 7, pc = r % 7;
    int h = wi * 7 + pr + 3; if (h >= IMG) h -= IMG;
    int w = wj * 7 + pc + 3; if (w >= IMG) w -= IMG;
    float4 v = reinterpret_cast<const float4*>(
        query + (((size_t)(b * 3136 + h * IMG + w)) << 8))[ch];
    u16* dst = &Xs[r][ch << 2];
    dst[0] = f2bf(v.x); dst[1] = f2bf(v.y); dst[2] = f2bf(v.z); dst[3] = f2bf(v.w);
  }
  __syncthreads();

  for (int hh = 0; hh < NHEADS; ++hh) {
    // ---- qkv for this head: 49 rows x (32q|32k|32v), 8 cols/task ----
    for (int task = tid; task < NTOK * 12; task += 256) {
      int r = task / 12, cg = task % 12;
      int c0 = cg << 3;
      int wcol;
      if (c0 < 32)      wcol = hh * 32 + c0;
      else if (c0 < 64) wcol = 256 + hh * 32 + (c0 - 32);
      else              wcol = 512 + hh * 32 + (c0 - 64);
      float acc[8];
      *reinterpret_cast<float4*>(&acc[0]) = *reinterpret_cast<const float4*>(b_qkv + wcol);
      *reinterpret_cast<float4*>(&acc[4]) = *reinterpret_cast<const float4*>(b_qkv + wcol + 4);
      const float* wp = w_qkv + wcol;
      const u16* xr = &Xs[r][0];
      #pragma unroll 2
      for (int i = 0; i < CDIM; i += 2) {
        u32 xp = *reinterpret_cast<const u32*>(xr + i);
        float x0 = bflo(xp), x1 = bfhi(xp);
        const float* w0p = wp + (size_t)i * 768;
        const float* w1p = wp + (size_t)(i + 1) * 768;
        float4 a0 = reinterpret_cast<const float4*>(w0p)[0];
        float4 a1 = reinterpret_cast<const float4*>(w0p)[1];
        float4 b0 = reinterpret_cast<const float4*>(w1p)[0];
        float4 b1 = reinterpret_cast<const float4*>(w1p)[1];
        acc[0] = fmaf(x0, a0.x, acc[0]); acc[1] = fmaf(x0, a0.y, acc[1]);
        acc[2] = fmaf(x0, a0.z, acc[2]); acc[3] = fmaf(x0, a0.w, acc[3]);
        acc[4] = fmaf(x0, a1.x, acc[4]); acc[5] = fmaf(x0, a1.y, acc[5]);
        acc[6] = fmaf(x0, a1.z, acc[6]); acc[7] = fmaf(x0, a1.w, acc[7]);
        acc[0] = fmaf(x1, b0.x, acc[0]); acc[1] = fmaf(x1, b0.y, acc[1]);
        acc[2] = fmaf(x1, b0.z, acc[2]); acc[3] = fmaf(x1, b0.w, acc[3]);
        acc[4] = fmaf(x1, b1.x, acc[4]); acc[5] = fmaf(x1, b1.y, acc[5]);
        acc[6] = fmaf(x1, b1.z, acc[6]); acc[7] = fmaf(x1, b1.w, acc[7]);
      }
      if (c0 < 32) {
        #pragma unroll
        for (int j = 0; j < 8; ++j) Qs[r][c0 + j] = acc[j] * SCALE;
      } else if (c0 < 64) {
        #pragma unroll
        for (int j = 0; j < 8; ++j) Kt[c0 - 32 + j][r] = acc[j];
      } else {
        #pragma unroll
        for (int j = 0; j < 8; ++j) Vs[r][c0 - 64 + j] = acc[j];
      }
    }
    __syncthreads();

    // ---- scores: S = (q*scale) @ k^T + bias + shift-mask ----
    for (int task = tid; task < NTOK * NTOK; task += 256) {
      int n = task / 49, m = task % 49;
      float s = 0.f;
      #pragma unroll 8
      for (int d = 0; d < HD; ++d) s = fmaf(Qs[n][d], Kt[d][m], s);
      int yn = n / 7, xn = n - yn * 7;
      int ym = m / 7, xm = m - ym * 7;
      int idx = (yn - ym + 6) * 13 + (xn - xm + 6);
      s += biasf[idx * 8 + hh];
      if (cls[n] != cls[m]) s -= 100.f;
      Ss[n][m] = s;
    }
    __syncthreads();

    // ---- softmax per row ----
    if (tid < NTOK) {
      float mx = -1e30f;
      for (int m = 0; m < NTOK; ++m) mx = fmaxf(mx, Ss[tid][m]);
      float sum = 0.f;
      for (int m = 0; m < NTOK; ++m) {
        float e = __expf(Ss[tid][m] - mx);
        Ss[tid][m] = e;
        sum += e;
      }
      float inv = 1.f / sum;
      for (int m = 0; m < NTOK; ++m) Ss[tid][m] *= inv;
    }
    __syncthreads();

    // ---- O_h = P @ V -> ws (bf16, layout [win][n][C], head slice hh*32) ----
    u16* obase = O + (size_t)win * NTOK * CDIM + hh * 32;
    for (int task = tid; task < NTOK * HD; task += 256) {
      int n = task >> 5, d = task & 31;
      float acc = 0.f;
      for (int m = 0; m < NTOK; ++m) acc = fmaf(Ss[n][m], Vs[m][d], acc);
      obase[(size_t)n * CDIM + d] = f2bf(acc);
    }
    __syncthreads();  // protect Qs/Kt/Vs/Ss before next head
  }
}

// ---------------- Kernel 2: output projection + window reverse + unroll ----------------
__global__ __launch_bounds__(256) void proj_kernel(
    const u16* __restrict__ O, const float* __restrict__ w_proj,
    const float* __restrict__ b_proj, float* __restrict__ out) {
  __shared__ __align__(16) u16 Os[NTOK][264];
  const int tid = threadIdx.x;
  const int win = blockIdx.x;
  const int b  = win >> 6;
  const int wi = (win >> 3) & 7;
  const int wj = win & 7;

  const u16* obase = O + (size_t)win * NTOK * CDIM;
  for (int t = tid; t < NTOK * 32; t += 256) {
    int r = t >> 5, ch = t & 31;
    *reinterpret_cast<uint4*>(&Os[r][ch << 3]) =
        reinterpret_cast<const uint4*>(obase + r * CDIM)[ch];
  }
  __syncthreads();

  for (int task = tid; task < NTOK * 32; task += 256) {
    int r = task >> 5, cg = task & 31;
    int c0 = cg << 3;
    float acc[8];
    *reinterpret_cast<float4*>(&acc[0]) = *reinterpret_cast<const float4*>(b_proj + c0);
    *reinterpret_cast<float4*>(&acc[4]) = *reinterpret_cast<const float4*>(b_proj + c0 + 4);
    const float* wp = w_proj + c0;
    const u16* xr = &Os[r][0];
    #pragma unroll 2
    for (int i = 0; i < CDIM; i += 2) {
      u32 xp = *reinterpret_cast<const u32*>(xr + i);
      float x0 = bflo(xp), x1 = bfhi(xp);
      const float* w0p = wp + (size_t)i * 256;
      const float* w1p = wp + (size_t)(i + 1) * 256;
      float4 a0 = reinterpret_cast<const float4*>(w0p)[0];
      float4 a1 = reinterpret_cast<const float4*>(w0p)[1];
      float4 b0 = reinterpret_cast<const float4*>(w1p)[0];
      float4 b1 = reinterpret_cast<const float4*>(w1p)[1];
      acc[0] = fmaf(x0, a0.x, acc[0]); acc[1] = fmaf(x0, a0.y, acc[1]);
      acc[2] = fmaf(x0, a0.z, acc[2]); acc[3] = fmaf(x0, a0.w, acc[3]);
      acc[4] = fmaf(x0, a1.x, acc[4]); acc[5] = fmaf(x0, a1.y, acc[5]);
      acc[6] = fmaf(x0, a1.z, acc[6]); acc[7] = fmaf(x0, a1.w, acc[7]);
      acc[0] = fmaf(x1, b0.x, acc[0]); acc[1] = fmaf(x1, b0.y, acc[1]);
      acc[2] = fmaf(x1, b0.z, acc[2]); acc[3] = fmaf(x1, b0.w, acc[3]);
      acc[4] = fmaf(x1, b1.x, acc[4]); acc[5] = fmaf(x1, b1.y, acc[5]);
      acc[6] = fmaf(x1, b1.z, acc[6]); acc[7] = fmaf(x1, b1.w, acc[7]);
    }
    // inverse roll: rolled (hs,ws) lands at ((hs+3)%56,(ws+3)%56)
    int pr = r / 7, pc = r % 7;
    int h = wi * 7 + pr + 3; if (h >= IMG) h -= IMG;
    int w = wj * 7 + pc + 3; if (w >= IMG) w -= IMG;
    float* op = out + (((size_t)(b * 3136 + h * IMG + w)) << 8) + c0;
    *reinterpret_cast<float4*>(op)     = *reinterpret_cast<const float4*>(&acc[0]);
    *reinterpret_cast<float4*>(op + 4) = *reinterpret_cast<const float4*>(&acc[4]);
  }
}

extern "C" void kernel_launch(void* const* d_in, const int* in_sizes, int n_in,
                              void* d_out, int out_size, void* d_ws, size_t ws_size,
                              hipStream_t stream) {
  const float* query      = (const float*)d_in[0];
  const float* w_qkv      = (const float*)d_in[1];
  const float* b_qkv      = (const float*)d_in[2];
  const float* w_proj     = (const float*)d_in[3];
  const float* b_proj     = (const float*)d_in[4];
  const float* bias_table = (const float*)d_in[5];
  // d_in[6]/d_in[7] = height/width (fixed 56 by setup_inputs; hardcoded)

  u16* O = (u16*)d_ws;  // 1024*49*256 bf16 = 25.7 MB pre-proj attention output

  attn_kernel<<<NWIN, 256, 0, stream>>>(query, w_qkv, b_qkv, bias_table, O);
  proj_kernel<<<NWIN, 256, 0, stream>>>(O, w_proj, b_proj, (float*)d_out);
}

// Round 3
// 280.012 us; speedup vs baseline: 6.2009x; 6.2009x over previous
//
#include <hip/hip_runtime.h>

// Shifted-window MSA, fixed shape: B=16, H=W=56, C=256, NH=8, hd=32, WS=7, SS=3.
// MFMA (16x16x32 bf16) version. Inputs fp32; intermediates bf16; accum fp32.
// d_ws layout (bytes):
//   [0, 25690112)              O   : pre-proj attn out, bf16 [1024][49][256]
//   [25690112, 26083328)       Wtq : w_qkv^T  bf16 [768][256]  (n-major, k contig)
//   [26083328, 26214400)       Wtp : w_proj^T bf16 [256][256]
// Total 26.2 MB.

#define IMG 56
#define NWIN 1024
#define SCALE 0.17677669529663687f

typedef unsigned short u16;
typedef unsigned int u32;
typedef __attribute__((ext_vector_type(8))) short short8;   // 8 bf16 (4 VGPRs)
typedef __attribute__((ext_vector_type(4))) float floatx4;  // MFMA C/D

__device__ __forceinline__ float bflo(u32 u) { return __uint_as_float(u << 16); }
__device__ __forceinline__ u16 f2bf(float f) {
  u32 u = __float_as_uint(f);
  return (u16)((u + 0x7fffu + ((u >> 16) & 1u)) >> 16);  // RNE
}

#define MFMA(a, b, c) __builtin_amdgcn_mfma_f32_16x16x32_bf16(a, b, c, 0, 0, 0)

// ---------------- Kernel 0: weight convert + transpose to bf16 ----------------
__global__ __launch_bounds__(256) void convert_kernel(
    const float* __restrict__ w_qkv, const float* __restrict__ w_proj,
    u16* __restrict__ Wtq, u16* __restrict__ Wtp) {
  int t = blockIdx.x * 256 + threadIdx.x;
  if (t < 196608) {           // t = k*768 + n
    int n = t % 768, k = t / 768;
    Wtq[n * 256 + k] = f2bf(w_qkv[t]);
  } else {                    // u = k*256 + n
    int u = t - 196608;
    int n = u % 256, k = u / 256;
    Wtp[n * 256 + k] = f2bf(w_proj[u]);
  }
}

// ---------------- Kernel 1: fused shifted-window QKV + attention (MFMA) --------
// LDS: Xs 33792 + Qs 5120 + Ks 5120 + Vt 4608 + Ps 9216 + biasb 2704
//      + bqs 3072 + cls 256 = 63888 B (< 64 KB)
__global__ __launch_bounds__(256) void attn_kernel(
    const float* __restrict__ query, const u16* __restrict__ Wtq,
    const float* __restrict__ b_qkv, const float* __restrict__ bias_table,
    u16* __restrict__ O) {
  __shared__ __align__(16) u16 Xs[64][264];  // window tokens bf16 (rows 49..63 zero)
  __shared__ __align__(16) u16 Qs[64][40];   // Q [token][dim]
  __shared__ __align__(16) u16 Ks[64][40];   // K [token][dim]
  __shared__ __align__(16) u16 Vt[32][72];   // V^T [dim][token]
  __shared__ __align__(16) u16 Ps[64][72];   // probs [token_q][token_k]
  __shared__ u16 biasb[169 * 8];             // rel-pos bias (bf16)
  __shared__ float bqs[768];                 // qkv bias fp32
  __shared__ int cls[64];

  const int tid = threadIdx.x;
  const int win = blockIdx.x;
  const int b  = win >> 6;
  const int wi = (win >> 3) & 7;
  const int wj = win & 7;
  const int lane = tid & 63;
  const int w = tid >> 6;         // wave id 0..3
  const int l15 = lane & 15;
  const int quad = lane >> 4;

  for (int t = tid; t < 169 * 8; t += 256) biasb[t] = f2bf(bias_table[t]);
  for (int t = tid; t < 768; t += 256) bqs[t] = b_qkv[t];
  if (tid < 64) {
    if (tid < 49) {
      int pr = tid / 7, pc = tid % 7;
      int rc = (wi < 7) ? 0 : ((pr < 4) ? 1 : 2);
      int cc = (wj < 7) ? 0 : ((pc < 4) ? 1 : 2);
      cls[tid] = rc * 3 + cc;
    } else cls[tid] = 0;
  }
  // zero pad rows 49..63 of Xs (264 u16 = 132 u32 per row)
  for (int t = tid; t < 15 * 132; t += 256) {
    int r = 49 + t / 132, c = (t % 132) * 2;
    *reinterpret_cast<u32*>(&Xs[r][c]) = 0;
  }
  // stage X (fp32 -> bf16): rolled[hs][ws] = x[(hs+3)%56][(ws+3)%56]
  for (int t = tid; t < 49 * 64; t += 256) {
    int r = t >> 6, ch = t & 63;
    int pr = r / 7, pc = r % 7;
    int hh = wi * 7 + pr + 3; if (hh >= IMG) hh -= IMG;
    int ww = wj * 7 + pc + 3; if (ww >= IMG) ww -= IMG;
    float4 v = reinterpret_cast<const float4*>(
        query + (((size_t)(b * 3136 + hh * IMG + ww)) << 8))[ch];
    u32 lo = (u32)f2bf(v.x) | ((u32)f2bf(v.y) << 16);
    u32 hi = (u32)f2bf(v.z) | ((u32)f2bf(v.w) << 16);
    u32* dst = reinterpret_cast<u32*>(&Xs[0][0]) + (r * 132 + ch * 2);
    dst[0] = lo; dst[1] = hi;
  }
  __syncthreads();

  const floatx4 zero4 = {0.f, 0.f, 0.f, 0.f};
  const int a = w & 1;        // M-tile pair: {2a, 2a+1}
  const int bb = w >> 1;      // N-tile triple: {3bb, 3bb+1, 3bb+2}

  for (int h = 0; h < 8; ++h) {
    // ---- QKV GEMM: X(64x256) @ Wq_head(256x96) ----
    int wcb[3];
    #pragma unroll
    for (int i = 0; i < 3; ++i) {
      int nt = 3 * bb + i;
      wcb[i] = (nt < 2) ? (h * 32 + nt * 16)
             : (nt < 4) ? (256 + h * 32 + (nt - 2) * 16)
                        : (512 + h * 32 + (nt - 4) * 16);
    }
    floatx4 acc[3][2];
    #pragma unroll
    for (int i = 0; i < 3; ++i) { acc[i][0] = zero4; acc[i][1] = zero4; }
    const u16* xb0 = &Xs[(2 * a + 0) * 16 + l15][quad * 8];
    const u16* xb1 = &Xs[(2 * a + 1) * 16 + l15][quad * 8];
    const u16* wtb[3];
    #pragma unroll
    for (int i = 0; i < 3; ++i)
      wtb[i] = Wtq + ((size_t)(wcb[i] + l15) << 8) + quad * 8;
    #pragma unroll
    for (int ks = 0; ks < 8; ++ks) {
      short8 a0 = *reinterpret_cast<const short8*>(xb0 + ks * 32);
      short8 a1 = *reinterpret_cast<const short8*>(xb1 + ks * 32);
      #pragma unroll
      for (int i = 0; i < 3; ++i) {
        short8 bfr = *reinterpret_cast<const short8*>(wtb[i] + ks * 32);
        acc[i][0] = MFMA(a0, bfr, acc[i][0]);
        acc[i][1] = MFMA(a1, bfr, acc[i][1]);
      }
    }
    // epilogue: +bias, bf16, scatter to Qs/Ks/Vt
    #pragma unroll
    for (int i = 0; i < 3; ++i) {
      int nt = 3 * bb + i;
      float bias = bqs[wcb[i] + l15];
      #pragma unroll
      for (int mtl = 0; mtl < 2; ++mtl) {
        int rowb = (2 * a + mtl) * 16 + 4 * quad;
        #pragma unroll
        for (int reg = 0; reg < 4; ++reg) {
          int row = rowb + reg;
          u16 hv = f2bf(acc[i][mtl][reg] + bias);
          if (nt < 2)      Qs[row][nt * 16 + l15] = hv;
          else if (nt < 4) Ks[row][(nt - 2) * 16 + l15] = hv;
          else             Vt[(nt - 4) * 16 + l15][row] = hv;
        }
      }
    }
    __syncthreads();

    // ---- scores: S = scale * Q @ K^T + bias + mask; wave w = M-tile w ----
    short8 qf = *reinterpret_cast<const short8*>(&Qs[16 * w + l15][quad * 8]);
    float sv[4][4];  // [nt][reg]
    #pragma unroll
    for (int nt = 0; nt < 4; ++nt) {
      short8 kf = *reinterpret_cast<const short8*>(&Ks[16 * nt + l15][quad * 8]);
      floatx4 sacc = MFMA(qf, kf, zero4);
      int col = 16 * nt + l15;
      #pragma unroll
      for (int reg = 0; reg < 4; ++reg) {
        int row = 16 * w + 4 * quad + reg;
        float s = sacc[reg] * SCALE;
        if (col >= 49) s = -1e30f;
        else if (row < 49) {
          int yn = row / 7, xn = row - yn * 7;
          int ym = col / 7, xm = col - ym * 7;
          int idx = (yn - ym + 6) * 13 + (xn - xm + 6);
          s += bflo((u32)biasb[idx * 8 + h]);
          if (cls[row] != cls[col]) s -= 100.f;
        }
        sv[nt][reg] = s;
      }
    }
    // softmax per row (16 lanes x 4 nt)
    #pragma unroll
    for (int reg = 0; reg < 4; ++reg) {
      float m = fmaxf(fmaxf(sv[0][reg], sv[1][reg]), fmaxf(sv[2][reg], sv[3][reg]));
      m = fmaxf(m, __shfl_xor(m, 1)); m = fmaxf(m, __shfl_xor(m, 2));
      m = fmaxf(m, __shfl_xor(m, 4)); m = fmaxf(m, __shfl_xor(m, 8));
      float sum = 0.f;
      #pragma unroll
      for (int nt = 0; nt < 4; ++nt) { float e = __expf(sv[nt][reg] - m); sv[nt][reg] = e; sum += e; }
      sum += __shfl_xor(sum, 1); sum += __shfl_xor(sum, 2);
      sum += __shfl_xor(sum, 4); sum += __shfl_xor(sum, 8);
      float inv = 1.f / sum;
      #pragma unroll
      for (int nt = 0; nt < 4; ++nt) sv[nt][reg] *= inv;
    }
    #pragma unroll
    for (int nt = 0; nt < 4; ++nt)
      #pragma unroll
      for (int reg = 0; reg < 4; ++reg)
        Ps[16 * w + 4 * quad + reg][16 * nt + l15] = f2bf(sv[nt][reg]);
    __syncthreads();

    // ---- PV: O_h = P(64x64) @ V(64x32); wave w = M-tile w ----
    floatx4 oacc[2] = {zero4, zero4};
    #pragma unroll
    for (int ks = 0; ks < 2; ++ks) {
      short8 pf = *reinterpret_cast<const short8*>(&Ps[16 * w + l15][ks * 32 + quad * 8]);
      #pragma unroll
      for (int ntl = 0; ntl < 2; ++ntl) {
        short8 vf = *reinterpret_cast<const short8*>(&Vt[16 * ntl + l15][ks * 32 + quad * 8]);
        oacc[ntl] = MFMA(pf, vf, oacc[ntl]);
      }
    }
    u16* obase = O + (size_t)win * 49 * 256;
    #pragma unroll
    for (int ntl = 0; ntl < 2; ++ntl) {
      #pragma unroll
      for (int reg = 0; reg < 4; ++reg) {
        int row = 16 * w + 4 * quad + reg;
        if (row < 49)
          obase[row * 256 + h * 32 + 16 * ntl + l15] = f2bf(oacc[ntl][reg]);
      }
    }
    __syncthreads();  // Qs/Ks/Vt/Ps reused next head
  }
}

// ---------------- Kernel 2: output projection (MFMA) + window reverse ----------
__global__ __launch_bounds__(256) void proj_kernel(
    const u16* __restrict__ O, const u16* __restrict__ Wtp,
    const float* __restrict__ b_proj, float* __restrict__ out) {
  __shared__ __align__(16) u16 Os[64][264];
  __shared__ float bps[256];
  const int tid = threadIdx.x;
  const int win = blockIdx.x;
  const int b  = win >> 6;
  const int wi = (win >> 3) & 7;
  const int wj = win & 7;
  const int lane = tid & 63;
  const int w = tid >> 6;
  const int l15 = lane & 15;
  const int quad = lane >> 4;

  if (tid < 256) bps[tid] = b_proj[tid];
  for (int t = tid; t < 15 * 132; t += 256) {  // zero pad rows 49..63
    int r = 49 + t / 132, c = (t % 132) * 2;
    *reinterpret_cast<u32*>(&Os[r][c]) = 0;
  }
  const u16* obase = O + (size_t)win * 49 * 256;
  for (int t = tid; t < 49 * 32; t += 256) {
    int r = t >> 5, ch = t & 31;
    *reinterpret_cast<uint4*>(&Os[r][ch << 3]) =
        reinterpret_cast<const uint4*>(obase + r * 256)[ch];
  }
  __syncthreads();

  const floatx4 zero4 = {0.f, 0.f, 0.f, 0.f};
  floatx4 acc[4][4];  // [i = local nt][mt]
  #pragma unroll
  for (int i = 0; i < 4; ++i)
    #pragma unroll
    for (int mt = 0; mt < 4; ++mt) acc[i][mt] = zero4;

  #pragma unroll
  for (int ks = 0; ks < 8; ++ks) {
    short8 af[4];
    #pragma unroll
    for (int mt = 0; mt < 4; ++mt)
      af[mt] = *reinterpret_cast<const short8*>(&Os[mt * 16 + l15][ks * 32 + quad * 8]);
    #pragma unroll
    for (int i = 0; i < 4; ++i) {
      int nt = 4 * w + i;
      short8 bfr = *reinterpret_cast<const short8*>(
          Wtp + ((size_t)(nt * 16 + l15) << 8) + ks * 32 + quad * 8);
      #pragma unroll
      for (int mt = 0; mt < 4; ++mt) acc[i][mt] = MFMA(af[mt], bfr, acc[i][mt]);
    }
  }

  #pragma unroll
  for (int i = 0; i < 4; ++i) {
    int col = (4 * w + i) * 16 + l15;
    float bias = bps[col];
    #pragma unroll
    for (int mt = 0; mt < 4; ++mt) {
      #pragma unroll
      for (int reg = 0; reg < 4; ++reg) {
        int row = mt * 16 + 4 * quad + reg;
        if (row < 49) {
          int pr = row / 7, pc = row - pr * 7;
          int hh = wi * 7 + pr + 3; if (hh >= IMG) hh -= IMG;
          int ww = wj * 7 + pc + 3; if (ww >= IMG) ww -= IMG;
          out[(((size_t)(b * 3136 + hh * IMG + ww)) << 8) + col] = acc[i][mt][reg] + bias;
        }
      }
    }
  }
}

extern "C" void kernel_launch(void* const* d_in, const int* in_sizes, int n_in,
                              void* d_out, int out_size, void* d_ws, size_t ws_size,
                              hipStream_t stream) {
  const float* query      = (const float*)d_in[0];
  const float* w_qkv      = (const float*)d_in[1];
  const float* b_qkv      = (const float*)d_in[2];
  const float* w_proj     = (const float*)d_in[3];
  const float* b_proj     = (const float*)d_in[4];
  const float* bias_table = (const float*)d_in[5];

  u16* O   = (u16*)d_ws;                       // 12,845,056 elems
  u16* Wtq = O + (size_t)1024 * 49 * 256;      // 196,608 elems
  u16* Wtp = Wtq + 768 * 256;                  // 65,536 elems

  convert_kernel<<<1024, 256, 0, stream>>>(w_qkv, w_proj, Wtq, Wtp);
  attn_kernel<<<NWIN, 256, 0, stream>>>(query, Wtq, b_qkv, bias_table, O);
  proj_kernel<<<NWIN, 256, 0, stream>>>(O, Wtp, b_proj, (float*)d_out);
}

// Round 4
// 264.084 us; speedup vs baseline: 6.5749x; 1.0603x over previous
//
#include <hip/hip_runtime.h>

// Shifted-window MSA, fixed shape: B=16, H=W=56, C=256, NH=8, hd=32, WS=7, SS=3.
// Batched-GEMM restructure:
//   convert   : w_qkv/w_proj -> transposed bf16 Wt[n][k]; zero pad block
//   qkv_gemm  : QKVb[m][768] = bf16(query) @ w_qkv + b   (MFMA 128x128x64 tiles)
//   attn      : per (window, head): gather QKV rows, scores+softmax+PV,
//               one __syncthreads, per-wave LDS slices + s_waitcnt fences
//   proj_gemm : out = O @ w_proj + b, fused inverse-roll scatter (fp32)
// ws (u16 elems): zpad[128] | Wtq[196608] | Wtp[65536] | QKVb[P*2408448] | O[P*802816]
// P = images per pass, picked from ws_size (P=4 fits 26.2 MB).

#define IMG 56
#define SCALE 0.17677669529663687f

typedef unsigned short u16;
typedef unsigned int u32;
typedef unsigned long long u64;
typedef __attribute__((ext_vector_type(8))) short short8;   // 8 bf16
typedef __attribute__((ext_vector_type(4))) float floatx4;  // MFMA C/D

__device__ __forceinline__ float bflo(u32 u) { return __uint_as_float(u << 16); }
__device__ __forceinline__ u16 f2bf(float f) {
  u32 u = __float_as_uint(f);
  return (u16)((u + 0x7fffu + ((u >> 16) & 1u)) >> 16);  // RNE
}
#define MFMA(a, b, c) __builtin_amdgcn_mfma_f32_16x16x32_bf16(a, b, c, 0, 0, 0)

__device__ __forceinline__ void gll16(const void* g, const void* l) {
  __builtin_amdgcn_global_load_lds(
      (const __attribute__((address_space(1))) void*)g,
      (__attribute__((address_space(3))) void*)l, 16, 0, 0);
}
#define FENCE_VM() __asm__ volatile("s_waitcnt vmcnt(0)" ::: "memory")
#define FENCE_LGKM() __asm__ volatile("s_waitcnt lgkmcnt(0)" ::: "memory")

// ---------------- Kernel 0: weight convert/transpose + zero pad ----------------
__global__ __launch_bounds__(256) void convert_kernel(
    const float* __restrict__ w_qkv, const float* __restrict__ w_proj,
    u16* __restrict__ zpad, u16* __restrict__ Wtq, u16* __restrict__ Wtp) {
  int t = blockIdx.x * 256 + threadIdx.x;
  if (t < 196608) {            // w_qkv[k][n], t = k*768+n
    int n = t % 768, k = t / 768;
    Wtq[n * 256 + k] = f2bf(w_qkv[t]);
  } else if (t < 262144) {     // w_proj[k][n]
    int u = t - 196608;
    int n = u & 255, k = u >> 8;
    Wtp[n * 256 + k] = f2bf(w_proj[u]);
  } else if (t < 262272) {
    zpad[t - 262144] = 0;
  }
}

// ---------------- Kernel 1: QKV GEMM (M=Mrows, N=768, K=256) ----------------
__global__ __launch_bounds__(256) void qkv_gemm(
    const float* __restrict__ query, const u16* __restrict__ Wtq,
    const float* __restrict__ b_qkv, u16* __restrict__ QKVb,
    int img0, int Mrows, int mtiles) {
  union LU {
    struct { u16 As[128][64]; u16 Bs[128][64]; } s;
    u16 Cs[128][144];
  };
  __shared__ LU L;
  __shared__ float bqs[128];
  const int tid = threadIdx.x;
  const int m0 = (blockIdx.x % mtiles) * 128;
  const int n0 = (blockIdx.x / mtiles) * 128;
  const int lane = tid & 63, w = tid >> 6;
  const int l15 = lane & 15, quad = lane >> 4;
  const int mq = w & 1, nq = w >> 1;
  if (tid < 128) bqs[tid] = b_qkv[n0 + tid];

  const floatx4 z4 = {0.f, 0.f, 0.f, 0.f};
  floatx4 acc[4][4];
  #pragma unroll
  for (int i = 0; i < 4; ++i)
    #pragma unroll
    for (int j = 0; j < 4; ++j) acc[i][j] = z4;

  const float* qbase = query + (size_t)img0 * 3136 * 256;

  for (int ki = 0; ki < 4; ++ki) {
    const int k0 = ki * 64;
    __syncthreads();
    // A stage: fp32 -> bf16, XOR-swizzled 16B chunks
    #pragma unroll
    for (int c = 0; c < 4; ++c) {
      int ch = tid + 256 * c;
      int row = ch >> 3, sp = ch & 7;
      int sub = sp ^ (row & 7);
      int gr = m0 + row; if (gr >= Mrows) gr = 0;
      const float* g = qbase + (size_t)gr * 256 + k0 + sub * 8;
      float4 v0 = *reinterpret_cast<const float4*>(g);
      float4 v1 = *reinterpret_cast<const float4*>(g + 4);
      short8 pk;
      pk[0] = (short)f2bf(v0.x); pk[1] = (short)f2bf(v0.y);
      pk[2] = (short)f2bf(v0.z); pk[3] = (short)f2bf(v0.w);
      pk[4] = (short)f2bf(v1.x); pk[5] = (short)f2bf(v1.y);
      pk[6] = (short)f2bf(v1.z); pk[7] = (short)f2bf(v1.w);
      *reinterpret_cast<short8*>(&L.s.As[row][sp * 8]) = pk;
    }
    // B stage: global_load_lds (bf16 weights), XOR-swizzled source
    #pragma unroll
    for (int c = 0; c < 4; ++c) {
      int ch = w * 256 + c * 64 + lane;
      int row = ch >> 3, sp = ch & 7;
      int sub = sp ^ (row & 7);
      const u16* g = Wtq + ((size_t)(n0 + row)) * 256 + k0 + sub * 8;
      gll16(g, (const char*)&L.s.Bs[0][0] + w * 4096 + c * 1024);
    }
    FENCE_VM(); FENCE_LGKM();
    __syncthreads();
    #pragma unroll
    for (int ks = 0; ks < 2; ++ks) {
      short8 af[4], bfv[4];
      #pragma unroll
      for (int mt = 0; mt < 4; ++mt) {
        int r = 64 * mq + 16 * mt + l15;
        af[mt] = *reinterpret_cast<const short8*>(
            &L.s.As[r][((4 * ks + quad) ^ (l15 & 7)) * 8]);
      }
      #pragma unroll
      for (int nt = 0; nt < 4; ++nt) {
        int r = 64 * nq + 16 * nt + l15;
        bfv[nt] = *reinterpret_cast<const short8*>(
            &L.s.Bs[r][((4 * ks + quad) ^ (l15 & 7)) * 8]);
      }
      #pragma unroll
      for (int mt = 0; mt < 4; ++mt)
        #pragma unroll
        for (int nt = 0; nt < 4; ++nt)
          acc[mt][nt] = MFMA(af[mt], bfv[nt], acc[mt][nt]);
    }
  }
  __syncthreads();
  // epilogue: +bias, bf16, LDS transpose for coalesced stores
  #pragma unroll
  for (int mt = 0; mt < 4; ++mt)
    #pragma unroll
    for (int nt = 0; nt < 4; ++nt) {
      float bias = bqs[64 * nq + 16 * nt + l15];
      #pragma unroll
      for (int reg = 0; reg < 4; ++reg) {
        int row = 64 * mq + 16 * mt + 4 * quad + reg;
        int col = 64 * nq + 16 * nt + l15;
        L.Cs[row][col] = f2bf(acc[mt][nt][reg] + bias);
      }
    }
  __syncthreads();
  int r = tid >> 1, half = tid & 1;
  if (m0 + r < Mrows) {
    u16* dst = QKVb + (size_t)(m0 + r) * 768 + n0 + half * 64;
    const u16* src = &L.Cs[r][half * 64];
    #pragma unroll
    for (int it = 0; it < 8; ++it)
      reinterpret_cast<uint4*>(dst)[it] = reinterpret_cast<const uint4*>(src)[it];
  }
}

// ---------------- Kernel 2: attention (1 block = window x 4 heads) ----------------
// LDS: wbuf 4x12KB (per-wave Q[64][32],K[64][32],Vt[32][64]; P/Ot overlays) + bias/cls
__global__ __launch_bounds__(256) void attn_kernel(
    const u16* __restrict__ QKVb, const float* __restrict__ bias_table,
    const u16* __restrict__ zpad, u16* __restrict__ O) {
  __shared__ __align__(16) u16 wbuf[4][6144];
  __shared__ u16 biasb[1352];
  __shared__ int cls[64];
  const int tid = threadIdx.x;
  const int winl = blockIdx.x >> 1;       // pass-local window
  const int hg = (blockIdx.x & 1) * 4;
  const int lane = tid & 63, w = tid >> 6;
  const int l15 = lane & 15, quad = lane >> 4;
  const int h = hg + w;                   // this wave's head
  const int bL = winl >> 6;
  const int wi = (winl >> 3) & 7;
  const int wj = winl & 7;

  for (int t = tid; t < 1352; t += 256) biasb[t] = f2bf(bias_table[t]);
  if (tid < 64) {
    if (tid < 49) {
      int pr = tid / 7, pc = tid % 7;
      int rc = (wi < 7) ? 0 : ((pr < 4) ? 1 : 2);
      int cc = (wj < 7) ? 0 : ((pc < 4) ? 1 : 2);
      cls[tid] = rc * 3 + cc;
    } else cls[tid] = 0;
  }
  __syncthreads();  // the only block-wide barrier

  u16* wb = wbuf[w];
  // ---- stage Q,K via global_load_lds (pad rows -> zpad) ----
  #pragma unroll
  for (int c = 0; c < 4; ++c) {
    int tok = c * 16 + (lane >> 2), sub = lane & 3;
    const u16 *gq, *gk;
    if (tok < 49) {
      int pr = tok / 7, pc = tok - pr * 7;
      int y = wi * 7 + pr + 3; if (y >= IMG) y -= IMG;
      int x = wj * 7 + pc + 3; if (x >= IMG) x -= IMG;
      size_t grow = (size_t)(bL * 3136 + y * IMG + x) * 768;
      gq = QKVb + grow + h * 32 + sub * 8;
      gk = QKVb + grow + 256 + h * 32 + sub * 8;
    } else {
      gq = zpad + sub * 8; gk = zpad + sub * 8;
    }
    gll16(gq, (const char*)wb + c * 1024);
    gll16(gk, (const char*)wb + 4096 + c * 1024);
  }
  // ---- stage V transposed (in-register) ----
  {
    int tok = lane;
    short8 v0 = {}, v1 = {}, v2 = {}, v3 = {};
    if (tok < 49) {
      int pr = tok / 7, pc = tok - pr * 7;
      int y = wi * 7 + pr + 3; if (y >= IMG) y -= IMG;
      int x = wj * 7 + pc + 3; if (x >= IMG) x -= IMG;
      const short8* g = reinterpret_cast<const short8*>(
          QKVb + (size_t)(bL * 3136 + y * IMG + x) * 768 + 512 + h * 32);
      v0 = g[0]; v1 = g[1]; v2 = g[2]; v3 = g[3];
    }
    #pragma unroll
    for (int d = 0; d < 8; ++d) {
      wb[4096 + (d     ) * 64 + tok] = (u16)v0[d];
      wb[4096 + (d +  8) * 64 + tok] = (u16)v1[d];
      wb[4096 + (d + 16) * 64 + tok] = (u16)v2[d];
      wb[4096 + (d + 24) * 64 + tok] = (u16)v3[d];
    }
  }
  FENCE_VM(); FENCE_LGKM();

  // ---- scores: S = scale * Q K^T + bias + mask ----
  const floatx4 z4 = {0.f, 0.f, 0.f, 0.f};
  short8 qf[4], kf[4];
  #pragma unroll
  for (int mt = 0; mt < 4; ++mt)
    qf[mt] = *reinterpret_cast<const short8*>(&wb[(16 * mt + l15) * 32 + quad * 8]);
  #pragma unroll
  for (int nt = 0; nt < 4; ++nt)
    kf[nt] = *reinterpret_cast<const short8*>(&wb[2048 + (16 * nt + l15) * 32 + quad * 8]);
  floatx4 sc[4][4];
  #pragma unroll
  for (int mt = 0; mt < 4; ++mt)
    #pragma unroll
    for (int nt = 0; nt < 4; ++nt) sc[mt][nt] = MFMA(qf[mt], kf[nt], z4);

  #pragma unroll
  for (int mt = 0; mt < 4; ++mt)
    #pragma unroll
    for (int nt = 0; nt < 4; ++nt) {
      int col = 16 * nt + l15;
      #pragma unroll
      for (int reg = 0; reg < 4; ++reg) {
        int row = 16 * mt + 4 * quad + reg;
        float s = sc[mt][nt][reg] * SCALE;
        if (col >= 49) s = -1e30f;
        else if (row < 49) {
          int yn = row / 7, xn = row - yn * 7;
          int ym = col / 7, xm = col - ym * 7;
          int idx = (yn - ym + 6) * 13 + (xn - xm + 6);
          s += bflo((u32)biasb[idx * 8 + h]);
          if (cls[row] != cls[col]) s -= 100.f;
        }
        sc[mt][nt][reg] = s;
      }
    }
  // ---- softmax per row (l15-span shuffles) ----
  #pragma unroll
  for (int mt = 0; mt < 4; ++mt)
    #pragma unroll
    for (int reg = 0; reg < 4; ++reg) {
      float m = fmaxf(fmaxf(sc[mt][0][reg], sc[mt][1][reg]),
                      fmaxf(sc[mt][2][reg], sc[mt][3][reg]));
      m = fmaxf(m, __shfl_xor(m, 1)); m = fmaxf(m, __shfl_xor(m, 2));
      m = fmaxf(m, __shfl_xor(m, 4)); m = fmaxf(m, __shfl_xor(m, 8));
      float sum = 0.f;
      #pragma unroll
      for (int nt = 0; nt < 4; ++nt) {
        float e = __expf(sc[mt][nt][reg] - m);
        sc[mt][nt][reg] = e; sum += e;
      }
      sum += __shfl_xor(sum, 1); sum += __shfl_xor(sum, 2);
      sum += __shfl_xor(sum, 4); sum += __shfl_xor(sum, 8);
      float inv = 1.f / sum;
      #pragma unroll
      for (int nt = 0; nt < 4; ++nt) sc[mt][nt][reg] *= inv;
    }
  // ---- P -> LDS (overlays Q,K region) ----
  #pragma unroll
  for (int mt = 0; mt < 4; ++mt)
    #pragma unroll
    for (int nt = 0; nt < 4; ++nt)
      #pragma unroll
      for (int reg = 0; reg < 4; ++reg)
        wb[(16 * mt + 4 * quad + reg) * 64 + 16 * nt + l15] = f2bf(sc[mt][nt][reg]);
  FENCE_LGKM();
  // ---- PV: O = P(64x64) @ V(64x32) ----
  floatx4 oa[4][2];
  #pragma unroll
  for (int mt = 0; mt < 4; ++mt) { oa[mt][0] = z4; oa[mt][1] = z4; }
  #pragma unroll
  for (int ks = 0; ks < 2; ++ks) {
    short8 pf[4], vf[2];
    #pragma unroll
    for (int mt = 0; mt < 4; ++mt)
      pf[mt] = *reinterpret_cast<const short8*>(
          &wb[(16 * mt + l15) * 64 + ks * 32 + quad * 8]);
    #pragma unroll
    for (int ntl = 0; ntl < 2; ++ntl)
      vf[ntl] = *reinterpret_cast<const short8*>(
          &wb[4096 + (16 * ntl + l15) * 64 + ks * 32 + quad * 8]);
    #pragma unroll
    for (int mt = 0; mt < 4; ++mt)
      #pragma unroll
      for (int ntl = 0; ntl < 2; ++ntl)
        oa[mt][ntl] = MFMA(pf[mt], vf[ntl], oa[mt][ntl]);
  }
  FENCE_LGKM();
  // ---- O transpose in LDS (overlays V region), coalesced store ----
  #pragma unroll
  for (int mt = 0; mt < 4; ++mt)
    #pragma unroll
    for (int ntl = 0; ntl < 2; ++ntl)
      #pragma unroll
      for (int reg = 0; reg < 4; ++reg)
        wb[4096 + (16 * mt + 4 * quad + reg) * 32 + 16 * ntl + l15] =
            f2bf(oa[mt][ntl][reg]);
  FENCE_LGKM();
  #pragma unroll
  for (int c = 0; c < 4; ++c) {
    int slot = c * 64 + lane;
    if (slot < 196) {
      int tok = slot >> 2, sub = slot & 3;
      uint4 v = *reinterpret_cast<const uint4*>(&wb[4096 + tok * 32 + sub * 8]);
      *reinterpret_cast<uint4*>(
          O + ((size_t)winl * 49 + tok) * 256 + h * 32 + sub * 8) = v;
    }
  }
}

// ---------------- Kernel 3: proj GEMM (M=Mrows, N=256, K=256) + scatter ----------
__global__ __launch_bounds__(256) void proj_gemm(
    const u16* __restrict__ O, const u16* __restrict__ Wtp,
    const float* __restrict__ b_proj, float* __restrict__ out,
    int img0, int Mrows, int mtiles) {
  __shared__ __align__(16) u16 As[128][64];
  __shared__ __align__(16) u16 Bs[128][64];
  __shared__ float bps[128];
  const int tid = threadIdx.x;
  const int m0 = (blockIdx.x % mtiles) * 128;
  const int n0 = (blockIdx.x / mtiles) * 128;
  const int lane = tid & 63, w = tid >> 6;
  const int l15 = lane & 15, quad = lane >> 4;
  const int mq = w & 1, nq = w >> 1;
  if (tid < 128) bps[tid] = b_proj[n0 + tid];

  const floatx4 z4 = {0.f, 0.f, 0.f, 0.f};
  floatx4 acc[4][4];
  #pragma unroll
  for (int i = 0; i < 4; ++i)
    #pragma unroll
    for (int j = 0; j < 4; ++j) acc[i][j] = z4;

  for (int ki = 0; ki < 4; ++ki) {
    const int k0 = ki * 64;
    __syncthreads();
    #pragma unroll
    for (int c = 0; c < 4; ++c) {
      int ch = w * 256 + c * 64 + lane;
      int row = ch >> 3, sp = ch & 7;
      int sub = sp ^ (row & 7);
      int gr = m0 + row; if (gr >= Mrows) gr = 0;
      gll16(O + (size_t)gr * 256 + k0 + sub * 8,
            (const char*)&As[0][0] + w * 4096 + c * 1024);
      gll16(Wtp + (size_t)(n0 + row) * 256 + k0 + sub * 8,
            (const char*)&Bs[0][0] + w * 4096 + c * 1024);
    }
    FENCE_VM();
    __syncthreads();
    #pragma unroll
    for (int ks = 0; ks < 2; ++ks) {
      short8 af[4], bfv[4];
      #pragma unroll
      for (int mt = 0; mt < 4; ++mt) {
        int r = 64 * mq + 16 * mt + l15;
        af[mt] = *reinterpret_cast<const short8*>(
            &As[r][((4 * ks + quad) ^ (l15 & 7)) * 8]);
      }
      #pragma unroll
      for (int nt = 0; nt < 4; ++nt) {
        int r = 64 * nq + 16 * nt + l15;
        bfv[nt] = *reinterpret_cast<const short8*>(
            &Bs[r][((4 * ks + quad) ^ (l15 & 7)) * 8]);
      }
      #pragma unroll
      for (int mt = 0; mt < 4; ++mt)
        #pragma unroll
        for (int nt = 0; nt < 4; ++nt)
          acc[mt][nt] = MFMA(af[mt], bfv[nt], acc[mt][nt]);
    }
  }
  // epilogue: +bias, inverse roll + window reverse scatter (fp32)
  #pragma unroll
  for (int nt = 0; nt < 4; ++nt) {
    int col = n0 + 64 * nq + 16 * nt + l15;
    float bias = bps[64 * nq + 16 * nt + l15];
    #pragma unroll
    for (int mt = 0; mt < 4; ++mt) {
      #pragma unroll
      for (int reg = 0; reg < 4; ++reg) {
        int row = m0 + 64 * mq + 16 * mt + 4 * quad + reg;
        if (row < Mrows) {
          u32 winl = (u32)row / 49u;
          int tok = row - (int)winl * 49;
          int bL = winl >> 6, wi = (winl >> 3) & 7, wj = winl & 7;
          int pr = tok / 7, pc = tok - pr * 7;
          int y = wi * 7 + pr + 3; if (y >= IMG) y -= IMG;
          int x = wj * 7 + pc + 3; if (x >= IMG) x -= IMG;
          out[(((size_t)((img0 + bL) * 3136 + y * IMG + x)) << 8) + col] =
              acc[mt][nt][reg] + bias;
        }
      }
    }
  }
}

extern "C" void kernel_launch(void* const* d_in, const int* in_sizes, int n_in,
                              void* d_out, int out_size, void* d_ws, size_t ws_size,
                              hipStream_t stream) {
  const float* query      = (const float*)d_in[0];
  const float* w_qkv      = (const float*)d_in[1];
  const float* b_qkv      = (const float*)d_in[2];
  const float* w_proj     = (const float*)d_in[3];
  const float* b_proj     = (const float*)d_in[4];
  const float* bias_table = (const float*)d_in[5];

  u16* wsu  = (u16*)d_ws;
  u16* zpad = wsu;                 // 128 u16 zeros
  u16* Wtq  = wsu + 128;           // 196608
  u16* Wtp  = wsu + 196736;        // 65536
  u16* QKVb = wsu + 262400;

  int P = 16;  // images per pass; shrink until buffers fit ws
  while (P > 1 && 2ull * (262400ull + (u64)P * 3211264ull) > (u64)ws_size) P >>= 1;
  u16* O = QKVb + (size_t)P * 2408448;
  const int npass  = 16 / P;
  const int Mrows  = P * 3136;
  const int mtiles = (Mrows + 127) / 128;

  convert_kernel<<<1025, 256, 0, stream>>>(w_qkv, w_proj, zpad, Wtq, Wtp);
  for (int p = 0; p < npass; ++p) {
    qkv_gemm<<<mtiles * 6, 256, 0, stream>>>(query, Wtq, b_qkv, QKVb,
                                             p * P, Mrows, mtiles);
    attn_kernel<<<P * 128, 256, 0, stream>>>(QKVb, bias_table, zpad, O);
    proj_gemm<<<mtiles * 2, 256, 0, stream>>>(O, Wtp, b_proj, (float*)d_out,
                                              p * P, Mrows, mtiles);
  }
}

// Round 5
// 233.937 us; speedup vs baseline: 7.4222x; 1.1289x over previous
//
#include <hip/hip_runtime.h>

// Shifted-window MSA, fixed shape: B=16, H=W=56, C=256, NH=8, hd=32, WS=7, SS=3.
// Pipeline:
//   convert : weights -> transposed bf16 Wt[n][k]; zpad; biasT[h][64][64] bf16
//   xconv   : query fp32 -> bf16, rolled + window-partitioned (window-token-major)
//   qkv_gemm: QKVb[m][768] = Xg @ w_qkv + b  (MFMA 128x128x64, gll16 A+B)
//   attn    : barrier-free; 1 wave = 1 (window, head); contiguous QKV rows
//   proj    : out = O @ w_proj + b, fused inverse-roll scatter (fp32)
// ws (u16): zpad[128]|Wtq[196608]|Wtp[65536]|biasT[32768]|Xg[P*802816]|
//           QKVb[P*2408448]|O[P*802816];  P = images/pass from ws_size.

#define IMG 56
#define SCALE 0.17677669529663687f

typedef unsigned short u16;
typedef unsigned int u32;
typedef unsigned long long u64;
typedef __attribute__((ext_vector_type(8))) short short8;   // 8 bf16
typedef __attribute__((ext_vector_type(4))) float floatx4;  // MFMA C/D

__device__ __forceinline__ float bflo(u32 u) { return __uint_as_float(u << 16); }
__device__ __forceinline__ u16 f2bf(float f) {
  u32 u = __float_as_uint(f);
  return (u16)((u + 0x7fffu + ((u >> 16) & 1u)) >> 16);  // RNE
}
#define MFMA(a, b, c) __builtin_amdgcn_mfma_f32_16x16x32_bf16(a, b, c, 0, 0, 0)

__device__ __forceinline__ void gll16(const void* g, const void* l) {
  __builtin_amdgcn_global_load_lds(
      (const __attribute__((address_space(1))) void*)g,
      (__attribute__((address_space(3))) void*)l, 16, 0, 0);
}
#define FENCE_VM() __asm__ volatile("s_waitcnt vmcnt(0)" ::: "memory")
#define FENCE_LGKM() __asm__ volatile("s_waitcnt lgkmcnt(0)" ::: "memory")

// ---------------- Kernel 0: weights + zpad + expanded bias table ----------------
__global__ __launch_bounds__(256) void convert_kernel(
    const float* __restrict__ w_qkv, const float* __restrict__ w_proj,
    const float* __restrict__ bias_table, u16* __restrict__ zpad,
    u16* __restrict__ Wtq, u16* __restrict__ Wtp, u16* __restrict__ biasT) {
  int t = blockIdx.x * 256 + threadIdx.x;
  if (t < 196608) {            // w_qkv[k][n]
    int n = t % 768, k = t / 768;
    Wtq[n * 256 + k] = f2bf(w_qkv[t]);
  } else if (t < 262144) {     // w_proj[k][n]
    int u = t - 196608;
    int n = u & 255, k = u >> 8;
    Wtp[n * 256 + k] = f2bf(w_proj[u]);
  } else if (t < 262272) {
    zpad[t - 262144] = 0;
  } else if (t < 295040) {     // biasT[h][row][col], zeros outside 49x49
    int idx = t - 262272;
    int h = idx >> 12, rr = (idx >> 6) & 63, cc = idx & 63;
    u16 v = 0;
    if (rr < 49 && cc < 49) {
      int yn = rr / 7, xn = rr - yn * 7;
      int ym = cc / 7, xm = cc - ym * 7;
      int bi = (yn - ym + 6) * 13 + (xn - xm + 6);
      v = f2bf(bias_table[bi * 8 + h]);
    }
    biasT[idx] = v;
  }
}

// ---------------- Kernel 1: roll + window-partition + fp32->bf16 ----------------
__global__ __launch_bounds__(256) void xconv_kernel(
    const float* __restrict__ query, u16* __restrict__ Xg, int img0) {
  int t = blockIdx.x * 256 + threadIdx.x;  // t = m*32 + cg
  int m = t >> 5, cg = t & 31;
  int winl = m / 49, tok = m - winl * 49;
  int bL = winl >> 6, wi = (winl >> 3) & 7, wj = winl & 7;
  int pr = tok / 7, pc = tok - pr * 7;
  int y = wi * 7 + pr + 3; if (y >= IMG) y -= IMG;
  int x = wj * 7 + pc + 3; if (x >= IMG) x -= IMG;
  const float* src =
      query + (((size_t)((img0 + bL) * 3136 + y * IMG + x)) << 8) + cg * 8;
  float4 v0 = reinterpret_cast<const float4*>(src)[0];
  float4 v1 = reinterpret_cast<const float4*>(src)[1];
  short8 pk;
  pk[0] = (short)f2bf(v0.x); pk[1] = (short)f2bf(v0.y);
  pk[2] = (short)f2bf(v0.z); pk[3] = (short)f2bf(v0.w);
  pk[4] = (short)f2bf(v1.x); pk[5] = (short)f2bf(v1.y);
  pk[6] = (short)f2bf(v1.z); pk[7] = (short)f2bf(v1.w);
  *reinterpret_cast<short8*>(Xg + (size_t)m * 256 + cg * 8) = pk;
}

// ---------------- Kernel 2: QKV GEMM (M=Mrows, N=768, K=256) ----------------
__global__ __launch_bounds__(256) void qkv_gemm(
    const u16* __restrict__ Xg, const u16* __restrict__ Wtq,
    const float* __restrict__ b_qkv, u16* __restrict__ QKVb,
    int Mrows, int mtiles) {
  union LU {
    struct { u16 As[128][64]; u16 Bs[128][64]; } s;
    u16 Cs[128][144];
  };
  __shared__ LU L;
  __shared__ float bqs[128];
  const int tid = threadIdx.x;
  const int n0 = (blockIdx.x % 6) << 7;   // n-inner: 6 consecutive blocks share A
  const int m0 = (blockIdx.x / 6) << 7;
  const int lane = tid & 63, w = tid >> 6;
  const int l15 = lane & 15, quad = lane >> 4;
  const int mq = w & 1, nq = w >> 1;
  if (tid < 128) bqs[tid] = b_qkv[n0 + tid];

  const floatx4 z4 = {0.f, 0.f, 0.f, 0.f};
  floatx4 acc[4][4];
  #pragma unroll
  for (int i = 0; i < 4; ++i)
    #pragma unroll
    for (int j = 0; j < 4; ++j) acc[i][j] = z4;

  for (int ki = 0; ki < 4; ++ki) {
    const int k0 = ki * 64;
    __syncthreads();
    #pragma unroll
    for (int c = 0; c < 4; ++c) {
      int e = (w * 4 + c) * 64 + lane;         // 0..1023
      int row = e >> 3, sp = e & 7, sub = sp ^ (row & 7);
      int gr = m0 + row; if (gr >= Mrows) gr = 0;
      gll16(Xg + (size_t)gr * 256 + k0 + sub * 8,
            (const char*)&L.s.As[0][0] + (w * 4 + c) * 1024);
      gll16(Wtq + (size_t)(n0 + row) * 256 + k0 + sub * 8,
            (const char*)&L.s.Bs[0][0] + (w * 4 + c) * 1024);
    }
    FENCE_VM();
    __syncthreads();
    #pragma unroll
    for (int ks = 0; ks < 2; ++ks) {
      short8 af[4], bfv[4];
      #pragma unroll
      for (int mt = 0; mt < 4; ++mt) {
        int r = 64 * mq + 16 * mt + l15;
        af[mt] = *reinterpret_cast<const short8*>(
            &L.s.As[r][((4 * ks + quad) ^ (l15 & 7)) * 8]);
      }
      #pragma unroll
      for (int nt = 0; nt < 4; ++nt) {
        int r = 64 * nq + 16 * nt + l15;
        bfv[nt] = *reinterpret_cast<const short8*>(
            &L.s.Bs[r][((4 * ks + quad) ^ (l15 & 7)) * 8]);
      }
      #pragma unroll
      for (int mt = 0; mt < 4; ++mt)
        #pragma unroll
        for (int nt = 0; nt < 4; ++nt)
          acc[mt][nt] = MFMA(af[mt], bfv[nt], acc[mt][nt]);
    }
  }
  __syncthreads();
  #pragma unroll
  for (int mt = 0; mt < 4; ++mt)
    #pragma unroll
    for (int nt = 0; nt < 4; ++nt) {
      float bias = bqs[64 * nq + 16 * nt + l15];
      #pragma unroll
      for (int reg = 0; reg < 4; ++reg) {
        int row = 64 * mq + 16 * mt + 4 * quad + reg;
        int col = 64 * nq + 16 * nt + l15;
        L.Cs[row][col] = f2bf(acc[mt][nt][reg] + bias);
      }
    }
  __syncthreads();
  int r = tid >> 1, half = tid & 1;
  if (m0 + r < Mrows) {
    u16* dst = QKVb + (size_t)(m0 + r) * 768 + n0 + half * 64;
    const u16* src = &L.Cs[r][half * 64];
    #pragma unroll
    for (int it = 0; it < 8; ++it)
      reinterpret_cast<uint4*>(dst)[it] = reinterpret_cast<const uint4*>(src)[it];
  }
}

// ---------------- Kernel 3: attention — barrier-free, 1 wave = (window, head) ----
__global__ __launch_bounds__(256) void attn_kernel(
    const u16* __restrict__ QKVb, const u16* __restrict__ biasT,
    const u16* __restrict__ zpad, u16* __restrict__ O) {
  __shared__ __align__(16) u16 wbuf[4][6144];  // per-wave: Q[64][32],K[64][32],Vt[32][64]
  const int tid = threadIdx.x;
  const int winl = blockIdx.x >> 1;
  const int hg = (blockIdx.x & 1) * 4;
  const int lane = tid & 63, w = tid >> 6;
  const int l15 = lane & 15, quad = lane >> 4;
  const int h = hg + w;
  const int wi = (winl >> 3) & 7;
  const int wj = winl & 7;
  const bool bndH = (wi == 7), bndV = (wj == 7);

  u16* wb = wbuf[w];
  const size_t wrow = (size_t)winl * 49;
  // ---- stage Q,K via gll16 (contiguous rows; pad tokens -> zpad) ----
  #pragma unroll
  for (int c = 0; c < 4; ++c) {
    int tok = c * 16 + (lane >> 2), sub = lane & 3;
    const u16 *gq, *gk;
    if (tok < 49) {
      const u16* g = QKVb + (wrow + tok) * 768 + h * 32 + sub * 8;
      gq = g; gk = g + 256;
    } else {
      gq = zpad + sub * 8; gk = zpad + sub * 8;
    }
    gll16(gq, (const char*)wb + c * 1024);
    gll16(gk, (const char*)wb + 4096 + c * 1024);
  }
  // ---- stage V transposed (registers -> LDS) ----
  {
    int tok = lane;
    short8 v0 = {}, v1 = {}, v2 = {}, v3 = {};
    if (tok < 49) {
      const short8* g = reinterpret_cast<const short8*>(
          QKVb + (wrow + tok) * 768 + 512 + h * 32);
      v0 = g[0]; v1 = g[1]; v2 = g[2]; v3 = g[3];
    }
    #pragma unroll
    for (int d = 0; d < 8; ++d) {
      wb[4096 + (d     ) * 64 + tok] = (u16)v0[d];
      wb[4096 + (d +  8) * 64 + tok] = (u16)v1[d];
      wb[4096 + (d + 16) * 64 + tok] = (u16)v2[d];
      wb[4096 + (d + 24) * 64 + tok] = (u16)v3[d];
    }
  }
  FENCE_VM(); FENCE_LGKM();

  // ---- scores ----
  const floatx4 z4 = {0.f, 0.f, 0.f, 0.f};
  short8 qf[4], kf[4];
  #pragma unroll
  for (int mt = 0; mt < 4; ++mt)
    qf[mt] = *reinterpret_cast<const short8*>(&wb[(16 * mt + l15) * 32 + quad * 8]);
  #pragma unroll
  for (int nt = 0; nt < 4; ++nt)
    kf[nt] = *reinterpret_cast<const short8*>(&wb[2048 + (16 * nt + l15) * 32 + quad * 8]);
  floatx4 sc[4][4];
  #pragma unroll
  for (int mt = 0; mt < 4; ++mt)
    #pragma unroll
    for (int nt = 0; nt < 4; ++nt) sc[mt][nt] = MFMA(qf[mt], kf[nt], z4);

  // per-nt column class / validity; per-(mt,reg) row class
  int ccls[4]; bool cok[4];
  #pragma unroll
  for (int nt = 0; nt < 4; ++nt) {
    int col = 16 * nt + l15;
    cok[nt] = col < 49;
    int yc = col / 7, xc = col - yc * 7;
    ccls[nt] = (bndH ? ((yc < 4) ? 1 : 2) : 0) * 3 + (bndV ? ((xc < 4) ? 1 : 2) : 0);
  }
  int rcls[4][4];
  #pragma unroll
  for (int mt = 0; mt < 4; ++mt)
    #pragma unroll
    for (int reg = 0; reg < 4; ++reg) {
      int row = 16 * mt + 4 * quad + reg;
      int yr = row / 7, xr = row - yr * 7;
      rcls[mt][reg] =
          (bndH ? ((yr < 4) ? 1 : 2) : 0) * 3 + (bndV ? ((xr < 4) ? 1 : 2) : 0);
    }
  const u16* btab = biasT + (h << 12);
  #pragma unroll
  for (int mt = 0; mt < 4; ++mt)
    #pragma unroll
    for (int nt = 0; nt < 4; ++nt) {
      int col = 16 * nt + l15;
      #pragma unroll
      for (int reg = 0; reg < 4; ++reg) {
        int row = 16 * mt + 4 * quad + reg;
        float s = sc[mt][nt][reg] * SCALE + bflo((u32)btab[(row << 6) + col]);
        if ((bndH || bndV) && rcls[mt][reg] != ccls[nt]) s -= 100.f;
        if (!cok[nt]) s = -1e30f;
        sc[mt][nt][reg] = s;
      }
    }
  // ---- softmax per row ----
  #pragma unroll
  for (int mt = 0; mt < 4; ++mt)
    #pragma unroll
    for (int reg = 0; reg < 4; ++reg) {
      float m = fmaxf(fmaxf(sc[mt][0][reg], sc[mt][1][reg]),
                      fmaxf(sc[mt][2][reg], sc[mt][3][reg]));
      m = fmaxf(m, __shfl_xor(m, 1)); m = fmaxf(m, __shfl_xor(m, 2));
      m = fmaxf(m, __shfl_xor(m, 4)); m = fmaxf(m, __shfl_xor(m, 8));
      float sum = 0.f;
      #pragma unroll
      for (int nt = 0; nt < 4; ++nt) {
        float e = __expf(sc[mt][nt][reg] - m);
        sc[mt][nt][reg] = e; sum += e;
      }
      sum += __shfl_xor(sum, 1); sum += __shfl_xor(sum, 2);
      sum += __shfl_xor(sum, 4); sum += __shfl_xor(sum, 8);
      float inv = 1.f / sum;
      #pragma unroll
      for (int nt = 0; nt < 4; ++nt) sc[mt][nt][reg] *= inv;
    }
  // ---- P -> LDS (overlays Q,K) ----
  #pragma unroll
  for (int mt = 0; mt < 4; ++mt)
    #pragma unroll
    for (int nt = 0; nt < 4; ++nt)
      #pragma unroll
      for (int reg = 0; reg < 4; ++reg)
        wb[(16 * mt + 4 * quad + reg) * 64 + 16 * nt + l15] = f2bf(sc[mt][nt][reg]);
  FENCE_LGKM();
  // ---- PV ----
  floatx4 oa[4][2];
  #pragma unroll
  for (int mt = 0; mt < 4; ++mt) { oa[mt][0] = z4; oa[mt][1] = z4; }
  #pragma unroll
  for (int ks = 0; ks < 2; ++ks) {
    short8 pf[4], vf[2];
    #pragma unroll
    for (int mt = 0; mt < 4; ++mt)
      pf[mt] = *reinterpret_cast<const short8*>(
          &wb[(16 * mt + l15) * 64 + ks * 32 + quad * 8]);
    #pragma unroll
    for (int ntl = 0; ntl < 2; ++ntl)
      vf[ntl] = *reinterpret_cast<const short8*>(
          &wb[4096 + (16 * ntl + l15) * 64 + ks * 32 + quad * 8]);
    #pragma unroll
    for (int mt = 0; mt < 4; ++mt)
      #pragma unroll
      for (int ntl = 0; ntl < 2; ++ntl)
        oa[mt][ntl] = MFMA(pf[mt], vf[ntl], oa[mt][ntl]);
  }
  FENCE_LGKM();
  // ---- O transpose (overlays Vt), coalesced store ----
  #pragma unroll
  for (int mt = 0; mt < 4; ++mt)
    #pragma unroll
    for (int ntl = 0; ntl < 2; ++ntl)
      #pragma unroll
      for (int reg = 0; reg < 4; ++reg)
        wb[4096 + (16 * mt + 4 * quad + reg) * 32 + 16 * ntl + l15] =
            f2bf(oa[mt][ntl][reg]);
  FENCE_LGKM();
  #pragma unroll
  for (int c = 0; c < 4; ++c) {
    int slot = c * 64 + lane;
    if (slot < 196) {
      int tok = slot >> 2, sub = slot & 3;
      uint4 v = *reinterpret_cast<const uint4*>(&wb[4096 + tok * 32 + sub * 8]);
      *reinterpret_cast<uint4*>(O + (wrow + tok) * 256 + h * 32 + sub * 8) = v;
    }
  }
}

// ---------------- Kernel 4: proj GEMM (M=Mrows, N=256) + inverse-roll scatter ----
__global__ __launch_bounds__(256) void proj_gemm(
    const u16* __restrict__ O, const u16* __restrict__ Wtp,
    const float* __restrict__ b_proj, float* __restrict__ out,
    int img0, int Mrows, int mtiles) {
  __shared__ __align__(16) u16 As[128][64];
  __shared__ __align__(16) u16 Bs[128][64];
  __shared__ float bps[128];
  const int tid = threadIdx.x;
  const int n0 = (blockIdx.x & 1) << 7;
  const int m0 = (blockIdx.x >> 1) << 7;
  const int lane = tid & 63, w = tid >> 6;
  const int l15 = lane & 15, quad = lane >> 4;
  const int mq = w & 1, nq = w >> 1;
  if (tid < 128) bps[tid] = b_proj[n0 + tid];

  const floatx4 z4 = {0.f, 0.f, 0.f, 0.f};
  floatx4 acc[4][4];
  #pragma unroll
  for (int i = 0; i < 4; ++i)
    #pragma unroll
    for (int j = 0; j < 4; ++j) acc[i][j] = z4;

  for (int ki = 0; ki < 4; ++ki) {
    const int k0 = ki * 64;
    __syncthreads();
    #pragma unroll
    for (int c = 0; c < 4; ++c) {
      int e = (w * 4 + c) * 64 + lane;
      int row = e >> 3, sp = e & 7, sub = sp ^ (row & 7);
      int gr = m0 + row; if (gr >= Mrows) gr = 0;
      gll16(O + (size_t)gr * 256 + k0 + sub * 8,
            (const char*)&As[0][0] + (w * 4 + c) * 1024);
      gll16(Wtp + (size_t)(n0 + row) * 256 + k0 + sub * 8,
            (const char*)&Bs[0][0] + (w * 4 + c) * 1024);
    }
    FENCE_VM();
    __syncthreads();
    #pragma unroll
    for (int ks = 0; ks < 2; ++ks) {
      short8 af[4], bfv[4];
      #pragma unroll
      for (int mt = 0; mt < 4; ++mt) {
        int r = 64 * mq + 16 * mt + l15;
        af[mt] = *reinterpret_cast<const short8*>(
            &As[r][((4 * ks + quad) ^ (l15 & 7)) * 8]);
      }
      #pragma unroll
      for (int nt = 0; nt < 4; ++nt) {
        int r = 64 * nq + 16 * nt + l15;
        bfv[nt] = *reinterpret_cast<const short8*>(
            &Bs[r][((4 * ks + quad) ^ (l15 & 7)) * 8]);
      }
      #pragma unroll
      for (int mt = 0; mt < 4; ++mt)
        #pragma unroll
        for (int nt = 0; nt < 4; ++nt)
          acc[mt][nt] = MFMA(af[mt], bfv[nt], acc[mt][nt]);
    }
  }
  #pragma unroll
  for (int nt = 0; nt < 4; ++nt) {
    int col = n0 + 64 * nq + 16 * nt + l15;
    float bias = bps[64 * nq + 16 * nt + l15];
    #pragma unroll
    for (int mt = 0; mt < 4; ++mt) {
      #pragma unroll
      for (int reg = 0; reg < 4; ++reg) {
        int row = m0 + 64 * mq + 16 * mt + 4 * quad + reg;
        if (row < Mrows) {
          u32 winl = (u32)row / 49u;
          int tok = row - (int)winl * 49;
          int bL = winl >> 6, wi = (winl >> 3) & 7, wj = winl & 7;
          int pr = tok / 7, pc = tok - pr * 7;
          int y = wi * 7 + pr + 3; if (y >= IMG) y -= IMG;
          int x = wj * 7 + pc + 3; if (x >= IMG) x -= IMG;
          out[(((size_t)((img0 + bL) * 3136 + y * IMG + x)) << 8) + col] =
              acc[mt][nt][reg] + bias;
        }
      }
    }
  }
}

extern "C" void kernel_launch(void* const* d_in, const int* in_sizes, int n_in,
                              void* d_out, int out_size, void* d_ws, size_t ws_size,
                              hipStream_t stream) {
  const float* query      = (const float*)d_in[0];
  const float* w_qkv      = (const float*)d_in[1];
  const float* b_qkv      = (const float*)d_in[2];
  const float* w_proj     = (const float*)d_in[3];
  const float* b_proj     = (const float*)d_in[4];
  const float* bias_table = (const float*)d_in[5];

  u16* wsu   = (u16*)d_ws;
  u16* zpad  = wsu;                 // 128
  u16* Wtq   = wsu + 128;           // 196608
  u16* Wtp   = wsu + 196736;        // 65536
  u16* biasT = wsu + 262272;        // 32768

  int P = 16;  // images per pass; shrink until buffers fit ws
  while (P > 1 && 2ull * (295040ull + (u64)P * 4014080ull) > (u64)ws_size) P >>= 1;
  u16* Xg   = wsu + 295040;                    // P*802816
  u16* QKVb = Xg + (size_t)P * 802816;         // P*2408448
  u16* Ob   = QKVb + (size_t)P * 2408448;      // P*802816
  const int npass  = 16 / P;
  const int Mrows  = P * 3136;
  const int mtiles = (Mrows + 127) / 128;

  convert_kernel<<<1153, 256, 0, stream>>>(w_qkv, w_proj, bias_table,
                                           zpad, Wtq, Wtp, biasT);
  for (int p = 0; p < npass; ++p) {
    xconv_kernel<<<Mrows / 8, 256, 0, stream>>>(query, Xg, p * P);
    qkv_gemm<<<mtiles * 6, 256, 0, stream>>>(Xg, Wtq, b_qkv, QKVb, Mrows, mtiles);
    attn_kernel<<<P * 128, 256, 0, stream>>>(QKVb, biasT, zpad, Ob);
    proj_gemm<<<mtiles * 2, 256, 0, stream>>>(Ob, Wtp, b_proj, (float*)d_out,
                                              p * P, Mrows, mtiles);
  }
}

// Round 6
// 229.760 us; speedup vs baseline: 7.5572x; 1.0182x over previous
//
#include <hip/hip_runtime.h>

// Shifted-window MSA, fixed shape: B=16, H=W=56, C=256, NH=8, hd=32, WS=7, SS=3.
// Pipeline:
//   convert : weights -> transposed bf16 Wt[n][k]; zpad; biasM[type][h] =
//             (rel-pos bias + shift mask + col-pad mask) in MFMA C-fragment layout
//   xconv   : query fp32 -> bf16, rolled + window-partitioned (window-token-major)
//   qkv_gemm: QKVb[m][768] = Xg @ w_qkv + b  (MFMA 128x128x64, gll16 A+B)
//   attn    : barrier-free; 1 wave = 1 (window, head); coalesced fragment bias
//   proj    : out = O @ w_proj + b; LDS-transposed epilogue, full-line stores
// ws (u16): zpad[128]|Wtq[196608]|Wtp[65536]|biasM[131072]|Xg[P*802816]|
//           QKVb[P*2408448]|O[P*802816];  P = images/pass from ws_size.

#define IMG 56
#define SCALE 0.17677669529663687f

typedef unsigned short u16;
typedef unsigned int u32;
typedef unsigned long long u64;
typedef __attribute__((ext_vector_type(8))) short short8;   // 8 bf16
typedef __attribute__((ext_vector_type(4))) float floatx4;  // MFMA C/D

__device__ __forceinline__ float bflo(u32 u) { return __uint_as_float(u << 16); }
__device__ __forceinline__ u16 f2bf(float f) {
  u32 u = __float_as_uint(f);
  return (u16)((u + 0x7fffu + ((u >> 16) & 1u)) >> 16);  // RNE
}
#define MFMA(a, b, c) __builtin_amdgcn_mfma_f32_16x16x32_bf16(a, b, c, 0, 0, 0)

__device__ __forceinline__ void gll16(const void* g, const void* l) {
  __builtin_amdgcn_global_load_lds(
      (const __attribute__((address_space(1))) void*)g,
      (__attribute__((address_space(3))) void*)l, 16, 0, 0);
}
#define FENCE_VM() __asm__ volatile("s_waitcnt vmcnt(0)" ::: "memory")
#define FENCE_LGKM() __asm__ volatile("s_waitcnt lgkmcnt(0)" ::: "memory")

// ---------------- Kernel 0: weights + zpad + fragment-layout bias tables --------
// biasM[type][h][mt][quad][l15][nt][reg] (bf16), type = bndH*2+bndV.
__global__ __launch_bounds__(256) void convert_kernel(
    const float* __restrict__ w_qkv, const float* __restrict__ w_proj,
    const float* __restrict__ bias_table, u16* __restrict__ zpad,
    u16* __restrict__ Wtq, u16* __restrict__ Wtp, u16* __restrict__ biasM) {
  int t = blockIdx.x * 256 + threadIdx.x;
  if (t < 196608) {            // w_qkv[k][n]
    int n = t % 768, k = t / 768;
    Wtq[n * 256 + k] = f2bf(w_qkv[t]);
  } else if (t < 262144) {     // w_proj[k][n]
    int u = t - 196608;
    int n = u & 255, k = u >> 8;
    Wtp[n * 256 + k] = f2bf(w_proj[u]);
  } else if (t < 262272) {
    zpad[t - 262144] = 0;
  } else if (t < 393344) {
    int idx = t - 262272;              // [type:2][h:3][mt:2][quad:2][l15:4][nt:2][reg:2]
    int type = idx >> 15;
    int r = idx & 32767;
    int h = r >> 12, mt = (r >> 10) & 3, quad = (r >> 8) & 3;
    int l15 = (r >> 4) & 15, nt = (r >> 2) & 3, reg = r & 3;
    int row = 16 * mt + 4 * quad + reg;
    int col = 16 * nt + l15;
    float v;
    if (col >= 49) v = -1e30f;
    else if (row >= 49) v = 0.f;
    else {
      int yn = row / 7, xn = row - yn * 7;
      int ym = col / 7, xm = col - ym * 7;
      v = bias_table[((yn - ym + 6) * 13 + (xn - xm + 6)) * 8 + h];
      int bndH = (type >> 1) & 1, bndV = type & 1;
      int rc = (bndH ? ((yn < 4) ? 1 : 2) : 0) * 3 + (bndV ? ((xn < 4) ? 1 : 2) : 0);
      int cc = (bndH ? ((ym < 4) ? 1 : 2) : 0) * 3 + (bndV ? ((xm < 4) ? 1 : 2) : 0);
      if (rc != cc) v -= 100.f;
    }
    biasM[idx] = f2bf(v);
  }
}

// ---------------- Kernel 1: roll + window-partition + fp32->bf16 ----------------
__global__ __launch_bounds__(256) void xconv_kernel(
    const float* __restrict__ query, u16* __restrict__ Xg, int img0) {
  int t = blockIdx.x * 256 + threadIdx.x;  // t = m*32 + cg
  int m = t >> 5, cg = t & 31;
  int winl = m / 49, tok = m - winl * 49;
  int bL = winl >> 6, wi = (winl >> 3) & 7, wj = winl & 7;
  int pr = tok / 7, pc = tok - pr * 7;
  int y = wi * 7 + pr + 3; if (y >= IMG) y -= IMG;
  int x = wj * 7 + pc + 3; if (x >= IMG) x -= IMG;
  const float* src =
      query + (((size_t)((img0 + bL) * 3136 + y * IMG + x)) << 8) + cg * 8;
  float4 v0 = reinterpret_cast<const float4*>(src)[0];
  float4 v1 = reinterpret_cast<const float4*>(src)[1];
  short8 pk;
  pk[0] = (short)f2bf(v0.x); pk[1] = (short)f2bf(v0.y);
  pk[2] = (short)f2bf(v0.z); pk[3] = (short)f2bf(v0.w);
  pk[4] = (short)f2bf(v1.x); pk[5] = (short)f2bf(v1.y);
  pk[6] = (short)f2bf(v1.z); pk[7] = (short)f2bf(v1.w);
  *reinterpret_cast<short8*>(Xg + (size_t)m * 256 + cg * 8) = pk;
}

// ---------------- Kernel 2: QKV GEMM (M=Mrows, N=768, K=256) ----------------
__global__ __launch_bounds__(256) void qkv_gemm(
    const u16* __restrict__ Xg, const u16* __restrict__ Wtq,
    const float* __restrict__ b_qkv, u16* __restrict__ QKVb,
    int Mrows, int mtiles) {
  union LU {
    struct { u16 As[128][64]; u16 Bs[128][64]; } s;
    u16 Cs[128][144];
  };
  __shared__ LU L;
  __shared__ float bqs[128];
  const int tid = threadIdx.x;
  const int n0 = (blockIdx.x % 6) << 7;   // n-inner: 6 consecutive blocks share A
  const int m0 = (blockIdx.x / 6) << 7;
  const int lane = tid & 63, w = tid >> 6;
  const int l15 = lane & 15, quad = lane >> 4;
  const int mq = w & 1, nq = w >> 1;
  if (tid < 128) bqs[tid] = b_qkv[n0 + tid];

  const floatx4 z4 = {0.f, 0.f, 0.f, 0.f};
  floatx4 acc[4][4];
  #pragma unroll
  for (int i = 0; i < 4; ++i)
    #pragma unroll
    for (int j = 0; j < 4; ++j) acc[i][j] = z4;

  for (int ki = 0; ki < 4; ++ki) {
    const int k0 = ki * 64;
    __syncthreads();
    #pragma unroll
    for (int c = 0; c < 4; ++c) {
      int e = (w * 4 + c) * 64 + lane;         // 0..1023
      int row = e >> 3, sp = e & 7, sub = sp ^ (row & 7);
      int gr = m0 + row; if (gr >= Mrows) gr = 0;
      gll16(Xg + (size_t)gr * 256 + k0 + sub * 8,
            (const char*)&L.s.As[0][0] + (w * 4 + c) * 1024);
      gll16(Wtq + (size_t)(n0 + row) * 256 + k0 + sub * 8,
            (const char*)&L.s.Bs[0][0] + (w * 4 + c) * 1024);
    }
    FENCE_VM();
    __syncthreads();
    #pragma unroll
    for (int ks = 0; ks < 2; ++ks) {
      short8 af[4], bfv[4];
      #pragma unroll
      for (int mt = 0; mt < 4; ++mt) {
        int r = 64 * mq + 16 * mt + l15;
        af[mt] = *reinterpret_cast<const short8*>(
            &L.s.As[r][((4 * ks + quad) ^ (l15 & 7)) * 8]);
      }
      #pragma unroll
      for (int nt = 0; nt < 4; ++nt) {
        int r = 64 * nq + 16 * nt + l15;
        bfv[nt] = *reinterpret_cast<const short8*>(
            &L.s.Bs[r][((4 * ks + quad) ^ (l15 & 7)) * 8]);
      }
      #pragma unroll
      for (int mt = 0; mt < 4; ++mt)
        #pragma unroll
        for (int nt = 0; nt < 4; ++nt)
          acc[mt][nt] = MFMA(af[mt], bfv[nt], acc[mt][nt]);
    }
  }
  __syncthreads();
  #pragma unroll
  for (int mt = 0; mt < 4; ++mt)
    #pragma unroll
    for (int nt = 0; nt < 4; ++nt) {
      float bias = bqs[64 * nq + 16 * nt + l15];
      #pragma unroll
      for (int reg = 0; reg < 4; ++reg) {
        int row = 64 * mq + 16 * mt + 4 * quad + reg;
        int col = 64 * nq + 16 * nt + l15;
        L.Cs[row][col] = f2bf(acc[mt][nt][reg] + bias);
      }
    }
  __syncthreads();
  int r = tid >> 1, half = tid & 1;
  if (m0 + r < Mrows) {
    u16* dst = QKVb + (size_t)(m0 + r) * 768 + n0 + half * 64;
    const u16* src = &L.Cs[r][half * 64];
    #pragma unroll
    for (int it = 0; it < 8; ++it)
      reinterpret_cast<uint4*>(dst)[it] = reinterpret_cast<const uint4*>(src)[it];
  }
}

// ---------------- Kernel 3: attention — barrier-free, 1 wave = (window, head) ----
__global__ __launch_bounds__(256) void attn_kernel(
    const u16* __restrict__ QKVb, const u16* __restrict__ biasM,
    const u16* __restrict__ zpad, u16* __restrict__ O) {
  __shared__ __align__(16) u16 wbuf[4][6144];  // per-wave: Q[64][32],K[64][32],Vt[32][64]
  const int tid = threadIdx.x;
  const int winl = blockIdx.x >> 1;
  const int hg = (blockIdx.x & 1) * 4;
  const int lane = tid & 63, w = tid >> 6;
  const int l15 = lane & 15, quad = lane >> 4;
  const int h = hg + w;
  const int wi = (winl >> 3) & 7;
  const int wj = winl & 7;
  const int type = ((wi == 7) ? 2 : 0) | ((wj == 7) ? 1 : 0);

  u16* wb = wbuf[w];
  const size_t wrow = (size_t)winl * 49;
  // ---- stage Q,K via gll16 (contiguous rows; pad tokens -> zpad) ----
  #pragma unroll
  for (int c = 0; c < 4; ++c) {
    int tok = c * 16 + (lane >> 2), sub = lane & 3;
    const u16 *gq, *gk;
    if (tok < 49) {
      const u16* g = QKVb + (wrow + tok) * 768 + h * 32 + sub * 8;
      gq = g; gk = g + 256;
    } else {
      gq = zpad + sub * 8; gk = zpad + sub * 8;
    }
    gll16(gq, (const char*)wb + c * 1024);
    gll16(gk, (const char*)wb + 4096 + c * 1024);
  }
  // ---- V rows (registers) ----
  short8 v0 = {}, v1 = {}, v2 = {}, v3 = {};
  {
    int tok = lane;
    if (tok < 49) {
      const short8* g = reinterpret_cast<const short8*>(
          QKVb + (wrow + tok) * 768 + 512 + h * 32);
      v0 = g[0]; v1 = g[1]; v2 = g[2]; v3 = g[3];
    }
  }
  // ---- bias fragment: 8 coalesced 16B loads/lane (issued early, overlap) ----
  const u16* bb = biasM + ((((type << 3) + h) << 12) + (quad << 8) + (l15 << 4));
  short8 bf0[4], bf1[4];
  #pragma unroll
  for (int mt = 0; mt < 4; ++mt) {
    bf0[mt] = *reinterpret_cast<const short8*>(bb + (mt << 10));
    bf1[mt] = *reinterpret_cast<const short8*>(bb + (mt << 10) + 8);
  }
  // ---- V transpose into LDS ----
  {
    int tok = lane;
    #pragma unroll
    for (int d = 0; d < 8; ++d) {
      wb[4096 + (d     ) * 64 + tok] = (u16)v0[d];
      wb[4096 + (d +  8) * 64 + tok] = (u16)v1[d];
      wb[4096 + (d + 16) * 64 + tok] = (u16)v2[d];
      wb[4096 + (d + 24) * 64 + tok] = (u16)v3[d];
    }
  }
  FENCE_VM(); FENCE_LGKM();

  // ---- scores ----
  const floatx4 z4 = {0.f, 0.f, 0.f, 0.f};
  short8 qf[4], kf[4];
  #pragma unroll
  for (int mt = 0; mt < 4; ++mt)
    qf[mt] = *reinterpret_cast<const short8*>(&wb[(16 * mt + l15) * 32 + quad * 8]);
  #pragma unroll
  for (int nt = 0; nt < 4; ++nt)
    kf[nt] = *reinterpret_cast<const short8*>(&wb[2048 + (16 * nt + l15) * 32 + quad * 8]);
  floatx4 sc[4][4];
  #pragma unroll
  for (int mt = 0; mt < 4; ++mt)
    #pragma unroll
    for (int nt = 0; nt < 4; ++nt) sc[mt][nt] = MFMA(qf[mt], kf[nt], z4);

  // ---- scale + fused bias/mask (no branches) ----
  #pragma unroll
  for (int mt = 0; mt < 4; ++mt)
    #pragma unroll
    for (int nt = 0; nt < 4; ++nt)
      #pragma unroll
      for (int reg = 0; reg < 4; ++reg) {
        u16 bv = (nt < 2) ? (u16)bf0[mt][(nt << 2) | reg]
                          : (u16)bf1[mt][((nt & 1) << 2) | reg];
        sc[mt][nt][reg] = sc[mt][nt][reg] * SCALE + bflo((u32)bv);
      }
  // ---- softmax per row ----
  #pragma unroll
  for (int mt = 0; mt < 4; ++mt)
    #pragma unroll
    for (int reg = 0; reg < 4; ++reg) {
      float m = fmaxf(fmaxf(sc[mt][0][reg], sc[mt][1][reg]),
                      fmaxf(sc[mt][2][reg], sc[mt][3][reg]));
      m = fmaxf(m, __shfl_xor(m, 1)); m = fmaxf(m, __shfl_xor(m, 2));
      m = fmaxf(m, __shfl_xor(m, 4)); m = fmaxf(m, __shfl_xor(m, 8));
      float sum = 0.f;
      #pragma unroll
      for (int nt = 0; nt < 4; ++nt) {
        float e = __expf(sc[mt][nt][reg] - m);
        sc[mt][nt][reg] = e; sum += e;
      }
      sum += __shfl_xor(sum, 1); sum += __shfl_xor(sum, 2);
      sum += __shfl_xor(sum, 4); sum += __shfl_xor(sum, 8);
      float inv = 1.f / sum;
      #pragma unroll
      for (int nt = 0; nt < 4; ++nt) sc[mt][nt][reg] *= inv;
    }
  // ---- P -> LDS (overlays Q,K) ----
  #pragma unroll
  for (int mt = 0; mt < 4; ++mt)
    #pragma unroll
    for (int nt = 0; nt < 4; ++nt)
      #pragma unroll
      for (int reg = 0; reg < 4; ++reg)
        wb[(16 * mt + 4 * quad + reg) * 64 + 16 * nt + l15] = f2bf(sc[mt][nt][reg]);
  FENCE_LGKM();
  // ---- PV ----
  floatx4 oa[4][2];
  #pragma unroll
  for (int mt = 0; mt < 4; ++mt) { oa[mt][0] = z4; oa[mt][1] = z4; }
  #pragma unroll
  for (int ks = 0; ks < 2; ++ks) {
    short8 pf[4], vf[2];
    #pragma unroll
    for (int mt = 0; mt < 4; ++mt)
      pf[mt] = *reinterpret_cast<const short8*>(
          &wb[(16 * mt + l15) * 64 + ks * 32 + quad * 8]);
    #pragma unroll
    for (int ntl = 0; ntl < 2; ++ntl)
      vf[ntl] = *reinterpret_cast<const short8*>(
          &wb[4096 + (16 * ntl + l15) * 64 + ks * 32 + quad * 8]);
    #pragma unroll
    for (int mt = 0; mt < 4; ++mt)
      #pragma unroll
      for (int ntl = 0; ntl < 2; ++ntl)
        oa[mt][ntl] = MFMA(pf[mt], vf[ntl], oa[mt][ntl]);
  }
  FENCE_LGKM();
  // ---- O transpose (overlays Vt), coalesced store ----
  #pragma unroll
  for (int mt = 0; mt < 4; ++mt)
    #pragma unroll
    for (int ntl = 0; ntl < 2; ++ntl)
      #pragma unroll
      for (int reg = 0; reg < 4; ++reg)
        wb[4096 + (16 * mt + 4 * quad + reg) * 32 + 16 * ntl + l15] =
            f2bf(oa[mt][ntl][reg]);
  FENCE_LGKM();
  #pragma unroll
  for (int c = 0; c < 4; ++c) {
    int slot = c * 64 + lane;
    if (slot < 196) {
      int tok = slot >> 2, sub = slot & 3;
      uint4 v = *reinterpret_cast<const uint4*>(&wb[4096 + tok * 32 + sub * 8]);
      *reinterpret_cast<uint4*>(O + (wrow + tok) * 256 + h * 32 + sub * 8) = v;
    }
  }
}

// ---------------- Kernel 4: proj GEMM (M=Mrows, N=256) + full-line scatter -------
__global__ __launch_bounds__(256) void proj_gemm(
    const u16* __restrict__ O, const u16* __restrict__ Wtp,
    const float* __restrict__ b_proj, float* __restrict__ out,
    int img0, int Mrows, int mtiles) {
  union LU {
    struct { u16 As[128][64]; u16 Bs[128][64]; } s;
    float Cs[64][132];   // epilogue transpose buffer (33792 B)
  };
  __shared__ LU L;
  __shared__ float bps[128];
  const int tid = threadIdx.x;
  const int n0 = (blockIdx.x & 1) << 7;
  const int m0 = (blockIdx.x >> 1) << 7;
  const int lane = tid & 63, w = tid >> 6;
  const int l15 = lane & 15, quad = lane >> 4;
  const int mq = w & 1, nq = w >> 1;
  if (tid < 128) bps[tid] = b_proj[n0 + tid];

  const floatx4 z4 = {0.f, 0.f, 0.f, 0.f};
  floatx4 acc[4][4];
  #pragma unroll
  for (int i = 0; i < 4; ++i)
    #pragma unroll
    for (int j = 0; j < 4; ++j) acc[i][j] = z4;

  for (int ki = 0; ki < 4; ++ki) {
    const int k0 = ki * 64;
    __syncthreads();
    #pragma unroll
    for (int c = 0; c < 4; ++c) {
      int e = (w * 4 + c) * 64 + lane;
      int row = e >> 3, sp = e & 7, sub = sp ^ (row & 7);
      int gr = m0 + row; if (gr >= Mrows) gr = 0;
      gll16(O + (size_t)gr * 256 + k0 + sub * 8,
            (const char*)&L.s.As[0][0] + (w * 4 + c) * 1024);
      gll16(Wtp + (size_t)(n0 + row) * 256 + k0 + sub * 8,
            (const char*)&L.s.Bs[0][0] + (w * 4 + c) * 1024);
    }
    FENCE_VM();
    __syncthreads();
    #pragma unroll
    for (int ks = 0; ks < 2; ++ks) {
      short8 af[4], bfv[4];
      #pragma unroll
      for (int mt = 0; mt < 4; ++mt) {
        int r = 64 * mq + 16 * mt + l15;
        af[mt] = *reinterpret_cast<const short8*>(
            &L.s.As[r][((4 * ks + quad) ^ (l15 & 7)) * 8]);
      }
      #pragma unroll
      for (int nt = 0; nt < 4; ++nt) {
        int r = 64 * nq + 16 * nt + l15;
        bfv[nt] = *reinterpret_cast<const short8*>(
            &L.s.Bs[r][((4 * ks + quad) ^ (l15 & 7)) * 8]);
      }
      #pragma unroll
      for (int mt = 0; mt < 4; ++mt)
        #pragma unroll
        for (int nt = 0; nt < 4; ++nt)
          acc[mt][nt] = MFMA(af[mt], bfv[nt], acc[mt][nt]);
    }
  }
  // epilogue: two 64-row passes through LDS, full-line fp32 stores
  #pragma unroll
  for (int mh = 0; mh < 2; ++mh) {
    __syncthreads();
    if (mq == mh) {
      #pragma unroll
      for (int nt = 0; nt < 4; ++nt) {
        float bias = bps[64 * nq + 16 * nt + l15];
        #pragma unroll
        for (int mt = 0; mt < 4; ++mt)
          #pragma unroll
          for (int reg = 0; reg < 4; ++reg)
            L.Cs[16 * mt + 4 * quad + reg][64 * nq + 16 * nt + l15] =
                acc[mt][nt][reg] + bias;
      }
    }
    __syncthreads();
    int r = tid >> 2, seg = tid & 3;
    int gr = m0 + mh * 64 + r;
    if (gr < Mrows) {
      u32 winl = (u32)gr / 49u;
      int tok = gr - (int)winl * 49;
      int bL = winl >> 6, wi = (winl >> 3) & 7, wj = winl & 7;
      int pr = tok / 7, pc = tok - pr * 7;
      int y = wi * 7 + pr + 3; if (y >= IMG) y -= IMG;
      int x = wj * 7 + pc + 3; if (x >= IMG) x -= IMG;
      float* op = out + (((size_t)((img0 + bL) * 3136 + y * IMG + x)) << 8) +
                  n0 + seg * 32;
      const float* src = &L.Cs[r][seg * 32];
      #pragma unroll
      for (int i = 0; i < 8; ++i)
        reinterpret_cast<float4*>(op)[i] = reinterpret_cast<const float4*>(src)[i];
    }
  }
}

extern "C" void kernel_launch(void* const* d_in, const int* in_sizes, int n_in,
                              void* d_out, int out_size, void* d_ws, size_t ws_size,
                              hipStream_t stream) {
  const float* query      = (const float*)d_in[0];
  const float* w_qkv      = (const float*)d_in[1];
  const float* b_qkv      = (const float*)d_in[2];
  const float* w_proj     = (const float*)d_in[3];
  const float* b_proj     = (const float*)d_in[4];
  const float* bias_table = (const float*)d_in[5];

  u16* wsu   = (u16*)d_ws;
  u16* zpad  = wsu;                 // 128
  u16* Wtq   = wsu + 128;           // 196608
  u16* Wtp   = wsu + 196736;        // 65536
  u16* biasM = wsu + 262272;        // 131072

  int P = 16;  // images per pass; shrink until buffers fit ws
  while (P > 1 && 2ull * (393344ull + (u64)P * 4014080ull) > (u64)ws_size) P >>= 1;
  u16* Xg   = wsu + 393344;                    // P*802816
  u16* QKVb = Xg + (size_t)P * 802816;         // P*2408448
  u16* Ob   = QKVb + (size_t)P * 2408448;      // P*802816
  const int npass  = 16 / P;
  const int Mrows  = P * 3136;
  const int mtiles = (Mrows + 127) / 128;

  convert_kernel<<<1537, 256, 0, stream>>>(w_qkv, w_proj, bias_table,
                                           zpad, Wtq, Wtp, biasM);
  for (int p = 0; p < npass; ++p) {
    xconv_kernel<<<Mrows / 8, 256, 0, stream>>>(query, Xg, p * P);
    qkv_gemm<<<mtiles * 6, 256, 0, stream>>>(Xg, Wtq, b_qkv, QKVb, Mrows, mtiles);
    attn_kernel<<<P * 128, 256, 0, stream>>>(QKVb, biasM, zpad, Ob);
    proj_gemm<<<mtiles * 2, 256, 0, stream>>>(Ob, Wtp, b_proj, (float*)d_out,
                                              p * P, Mrows, mtiles);
  }
}